// Round 26
// baseline (87.231 us; speedup 1.0000x reference)
//
#include <hip/hip_runtime.h>
#include <math.h>

#define NB 16
#define NS 4096
#define ND 1024
#define NH 16
#define LUTN 4096
#define NC 32            // s-chunks (grid = NB*NC = 512 blocks, 2/CU)
#define SC (NS / NC)     // 128 rows per block
#define RG 8             // rows per buffer (vA/vB/vC rotation)
#define NG (SC / RG)     // 16 groups

#define KF   651.8986469044033f      // LUT_SIZE / (2*pi)
#define PHIF 1.6180339887498949f
#define REVF 2.44140625e-4f          // 1/4096 (exact) — LUT step in revolutions
#define INV2PI 0.15915494309189535f  // 1/(2*pi): radians -> revolutions
#define EXPC 0.1275174394255169f     // log2(e) / sqrt(2*dh)

// workspace layout, in floats
#define OFF_P     0          // P[NC][NB][NH][ND] f32 = 8388608 floats (33.5 MB)
#define OFF_ZPART 8388608    // [NC][NB][NH] = 8192

// Non-draining barrier (m201 8-phase pattern): my LDS writes visible
// (lgkmcnt(0)), then raw s_barrier — in-flight global loads to REGISTERS
// survive (no cross-wave visibility needed for them). sched_barrier(0)
// pins ordering so the compiler doesn't hoist LDS reads / reg uses across
// (learn_hip rule #18). NO "memory" clobber (R7's codegen poison).
#define PIPE_BARRIER() do {                                  \
    asm volatile("s_waitcnt lgkmcnt(0)");                    \
    __builtin_amdgcn_sched_barrier(0);                       \
    __builtin_amdgcn_s_barrier();                            \
    __builtin_amdgcn_sched_barrier(0);                       \
} while (0)

// 16-lane-group sum via DPP row_shr (pure VALU); lane 16k+15 holds the sum.
__device__ __forceinline__ float dpp_reduce16(float p) {
    int y;
    y = __builtin_amdgcn_update_dpp(0, __float_as_int(p), 0x111, 0xF, 0xF, true);
    p += __int_as_float(y);
    y = __builtin_amdgcn_update_dpp(0, __float_as_int(p), 0x112, 0xF, 0xF, true);
    p += __int_as_float(y);
    y = __builtin_amdgcn_update_dpp(0, __float_as_int(p), 0x114, 0xF, 0xF, true);
    p += __int_as_float(y);
    y = __builtin_amdgcn_update_dpp(0, __float_as_int(p), 0x118, 0xF, 0xF, true);
    p += __int_as_float(y);
    return p;
}

#if __has_builtin(__builtin_amdgcn_exp2f)
#define EXP2F(x) __builtin_amdgcn_exp2f(x)
#else
#define EXP2F(x) exp2f(x)
#endif

// Packed FP32 FMA (VOP3P). src1 low/high half broadcast via op_sel.
#define PKFMA_LO(acc, e2, v2) \
    asm("v_pk_fma_f32 %0, %1, %2, %0 op_sel:[0,0,0] op_sel_hi:[1,0,1]" \
        : "+v"(acc) : "v"(e2), "v"(v2))
#define PKFMA_HI(acc, e2, v2) \
    asm("v_pk_fma_f32 %0, %1, %2, %0 op_sel:[0,1,0] op_sel_hi:[1,1,1]" \
        : "+v"(acc) : "v"(e2), "v"(v2))

// Fused scores + unnormalized per-head context, one pass over cached.
// R26: depth-2 load pipeline. R25's ledger shows ~zero overlap: BW-delivery
// of a group (~5750 cyc at the 2-block/CU HBM share) vs a ~1024-cyc ACC
// hiding window -> score throttles on delivery every group. Loads now issue
// TWO periods ahead (vA/vB/vC rotation, ~6800-cyc cover) and survive one
// barrier because PIPE_BARRIER drains lgkm only (loads land in registers;
// skipping the vmcnt drain is semantically sound). se WAR distance is 2
// groups = the double-buffer: reaching bar(g+1) implies ACC(g) done, and
// score(g+2) (the se[g&1] rewriter) runs only after bar(g+1).
__global__ __launch_bounds__(256, 2) void k_fused(const float* __restrict__ cached,
                                                  const float* __restrict__ x,
                                                  const float* __restrict__ t,
                                                  const float* __restrict__ wq,
                                                  const float* __restrict__ bq,
                                                  const float* __restrict__ wk,
                                                  const float* __restrict__ bk,
                                                  float* __restrict__ ws) {
    __shared__ float se[2][RG][16];    // e broadcast, double-buffered (1 KB)
    int tid = threadIdx.x;
    int b = blockIdx.x >> 5;           // / NC
    int c = blockIdx.x & (NC - 1);
    int s0 = c * SC;
    int m = tid * 4;

    // per-column constants: arg_rev = v * krR + kdR  (revolutions)
    float4 wkv = *(const float4*)(wk + m);
    float4 kbv = *(const float4*)(bk + m);
    float4 krR;
    krR.x = INV2PI / (1.0f + fabsf(wkv.x));
    krR.y = INV2PI / (1.0f + fabsf(wkv.y));
    krR.z = INV2PI / (1.0f + fabsf(wkv.z));
    krR.w = INV2PI / (1.0f + fabsf(wkv.w));

    float tphi = t[b] * PHIF;
    float4 xv = *(const float4*)(x + b * ND + m);
    float4 wqv = *(const float4*)(wq + m);
    float4 bqv = *(const float4*)(bq + m);
    float4 kdR;   // bk/(2pi) - rint(theta_q*KF)*REVF  (query stays quantized)
    kdR.x = kbv.x * INV2PI - rintf((xv.x / (1.0f + fabsf(wqv.x)) + bqv.x + tphi) * KF) * REVF;
    kdR.y = kbv.y * INV2PI - rintf((xv.y / (1.0f + fabsf(wqv.y)) + bqv.y + tphi) * KF) * REVF;
    kdR.z = kbv.z * INV2PI - rintf((xv.z / (1.0f + fabsf(wqv.z)) + bqv.z + tphi) * KF) * REVF;
    kdR.w = kbv.w * INV2PI - rintf((xv.w / (1.0f + fabsf(wqv.w)) + bqv.w + tphi) * KF) * REVF;

    // acc2[p][q] = (ctxh[2p][col q], ctxh[2p+1][col q]) — 64 VGPRs
    float2 acc2[8][4];
    #pragma unroll
    for (int p = 0; p < 8; ++p)
        #pragma unroll
        for (int q = 0; q < 4; ++q) acc2[p][q] = make_float2(0.f, 0.f);
    float zacc = 0.f;

    const float* base = cached + ((size_t)b * NS + s0) * ND + m;
    float4 vA[RG], vB[RG], vC[RG];     // 3 buffers: depth-2 pipeline (96 VGPR)

#define LOADG(dst, g) { \
    const float* bp = base + (size_t)(g) * (RG * ND); \
    _Pragma("unroll") \
    for (int r = 0; r < RG; ++r) dst[r] = *(const float4*)(bp + (size_t)r * ND); }

    // slim score: one fma + one v_cos per element (v_cos takes revolutions)
#define SCOREG(v, buf) { \
    _Pragma("unroll") \
    for (int r = 0; r < RG; ++r) { \
        float c0 = __builtin_amdgcn_cosf(fmaf(v[r].x, krR.x, kdR.x)); \
        float c1 = __builtin_amdgcn_cosf(fmaf(v[r].y, krR.y, kdR.y)); \
        float c2 = __builtin_amdgcn_cosf(fmaf(v[r].z, krR.z, kdR.z)); \
        float c3 = __builtin_amdgcn_cosf(fmaf(v[r].w, krR.w, kdR.w)); \
        float p = (c0 + c1) + (c2 + c3); \
        p = dpp_reduce16(p); \
        float e = EXP2F(p * EXPC);   /* |score| <= 5.66, no max pass */ \
        zacc += e;                   /* valid in lanes 15 mod 16 */ \
        if ((tid & 15) == 15) se[buf][r][tid >> 4] = e; \
    } }

#define ACC4P(v, buf) { \
    _Pragma("unroll") \
    for (int r = 0; r < RG; ++r) { \
        const float2* s2 = (const float2*)se[buf][r]; \
        float2 vxy = make_float2(v[r].x, v[r].y); \
        float2 vzw = make_float2(v[r].z, v[r].w); \
        _Pragma("unroll") \
        for (int p = 0; p < 8; ++p) { \
            float2 e2 = s2[p]; \
            PKFMA_LO(acc2[p][0], e2, vxy); \
            PKFMA_HI(acc2[p][1], e2, vxy); \
            PKFMA_LO(acc2[p][2], e2, vzw); \
            PKFMA_HI(acc2[p][3], e2, vzw); \
        } \
    } }

    // body(g): score(g) from regs -> lgkm-only barrier (in-flight loads
    // survive) -> issue load(g+2) -> ACC(g). Load->use distance = 2 periods.
#define BODY(vcur, vnext2, g) { \
    SCOREG(vcur, (g) & 1) \
    PIPE_BARRIER(); \
    if ((g) + 2 < NG) { LOADG(vnext2, (g) + 2) } \
    ACC4P(vcur, (g) & 1) }

    LOADG(vA, 0)
    LOADG(vB, 1)
    for (int gp = 0; gp < NG - 1; gp += 3) {   // gp = 0,3,6,9,12 -> g 0..14
        BODY(vA, vC, gp)
        BODY(vB, vA, gp + 1)
        BODY(vC, vB, gp + 2)
    }
    BODY(vA, vC, NG - 1)                        // g = 15 (15%3==0 -> vA)
#undef BODY
#undef ACC4P
#undef SCOREG
#undef LOADG

    // write per-head context partials, coalesced per h
    float* P = ws + OFF_P + (size_t)(c * NB + b) * (NH * ND) + m;
    #pragma unroll
    for (int p = 0; p < 8; ++p) {
        float4 lo = make_float4(acc2[p][0].x, acc2[p][1].x, acc2[p][2].x, acc2[p][3].x);
        float4 hi = make_float4(acc2[p][0].y, acc2[p][1].y, acc2[p][2].y, acc2[p][3].y);
        *(float4*)(P + (2 * p) * ND) = lo;
        *(float4*)(P + (2 * p + 1) * ND) = hi;
    }
    if ((tid & 15) == 15)
        ws[OFF_ZPART + (c * NB + b) * NH + (tid >> 4)] = zacc;
}

// k_out with folded Z-normalization: each block computes the 16 invZ values
// for its batch from ZPART (8K floats, L2-hot). Saves the k_z launch.
__global__ __launch_bounds__(256) void k_out(const float* __restrict__ t,
                                             const float* __restrict__ wo,
                                             const float* __restrict__ bo,
                                             const float* __restrict__ osc,
                                             const float* __restrict__ ws,
                                             float* __restrict__ out) {
    __shared__ float red[4][64];
    __shared__ float sinvz[NH];
    int bid = blockIdx.x;          // NB*16 = 256
    int b = bid >> 4, mc = bid & 15;
    int tid = threadIdx.x;
    int cq = tid >> 6, ml = tid & 63;
    int m = mc * 64 + ml;
    if (tid < NH) {
        float s = 0.f;
        #pragma unroll
        for (int c = 0; c < NC; ++c)
            s += ws[OFF_ZPART + (c * NB + b) * NH + tid];
        sinvz[tid] = 1.0f / s;
    }
    __syncthreads();
    const float* P = ws + OFF_P;
    float ctx = 0.f;
    #pragma unroll
    for (int h = 0; h < NH; ++h) {
        float s = 0.f;
        #pragma unroll
        for (int i = 0; i < NC / 4; ++i) {
            int c = cq * (NC / 4) + i;
            s += P[(size_t)(c * NB + b) * (NH * ND) + h * ND + m];
        }
        ctx = fmaf(s, sinvz[h], ctx);
    }
    red[cq][ml] = ctx;
    __syncthreads();
    if (cq == 0) {
        ctx = ((red[0][ml] + red[1][ml]) + (red[2][ml] + red[3][ml]));
        float theta = ctx / (1.0f + fabsf(wo[m])) + bo[m] + t[b] * PHIF;
        int idx = ((int)rintf(theta * KF)) & (LUTN - 1);
        float ang = (float)idx * (2.0f * 3.14159265358979323846f / LUTN);
        // precise libm trig: bit-matches the np table entries
        out[b * ND + m] = osc[m] * (cosf(ang) + sinf(ang));
    }
}

extern "C" void kernel_launch(void* const* d_in, const int* in_sizes, int n_in,
                              void* d_out, int out_size, void* d_ws, size_t ws_size,
                              hipStream_t stream) {
    const float* x      = (const float*)d_in[0];
    const float* cached = (const float*)d_in[1];
    const float* t      = (const float*)d_in[2];
    const float* wq     = (const float*)d_in[3];
    const float* bq     = (const float*)d_in[4];
    const float* wk     = (const float*)d_in[5];
    const float* bk     = (const float*)d_in[6];
    const float* wo     = (const float*)d_in[7];
    const float* bo     = (const float*)d_in[8];
    const float* osc    = (const float*)d_in[9];
    float* ws  = (float*)d_ws;
    float* out = (float*)d_out;

    k_fused<<<NB * NC, 256, 0, stream>>>(cached, x, t, wq, bq, wk, bk, ws);
    k_out<<<NB * (ND / 64), 256, 0, stream>>>(t, wo, bo, osc, ws, out);
}

// Round 27
// 57.500 us; speedup vs baseline: 1.5171x; 1.5171x over previous
//
#include <hip/hip_runtime.h>
#include <hip/hip_fp16.h>
#include <math.h>

#define NB 16
#define NS 4096
#define ND 1024
#define NH 16
#define LUTN 4096
#define NC 32            // s-chunks (grid = NB*NC = 512 blocks, 2/CU)
#define SC (NS / NC)     // 128 rows per block
#define RG 8             // rows per buffer (vA/vB ping-pong) — R23-proven
#define NG (SC / RG)     // 16 groups

#define KF   651.8986469044033f      // LUT_SIZE / (2*pi)
#define PHIF 1.6180339887498949f
#define REVF 2.44140625e-4f          // 1/4096 (exact) — LUT step in revolutions
#define INV2PI 0.15915494309189535f  // 1/(2*pi): radians -> revolutions
#define EXPC 0.1275174394255169f     // log2(e) / sqrt(2*dh)

// workspace layout
// P: f16 partials [NC][NB][NH][ND] = 8388608 halves = 16.7 MB (at ws base)
#define OFF_ZPART 8388608    // float index: [NC][NB][NH] = 8192 (byte 33.5MB, clear of P)

// 16-lane-group sum via DPP row_shr (pure VALU); lane 16k+15 holds the sum.
__device__ __forceinline__ float dpp_reduce16(float p) {
    int y;
    y = __builtin_amdgcn_update_dpp(0, __float_as_int(p), 0x111, 0xF, 0xF, true);
    p += __int_as_float(y);
    y = __builtin_amdgcn_update_dpp(0, __float_as_int(p), 0x112, 0xF, 0xF, true);
    p += __int_as_float(y);
    y = __builtin_amdgcn_update_dpp(0, __float_as_int(p), 0x114, 0xF, 0xF, true);
    p += __int_as_float(y);
    y = __builtin_amdgcn_update_dpp(0, __float_as_int(p), 0x118, 0xF, 0xF, true);
    p += __int_as_float(y);
    return p;
}

#if __has_builtin(__builtin_amdgcn_exp2f)
#define EXP2F(x) __builtin_amdgcn_exp2f(x)
#else
#define EXP2F(x) exp2f(x)
#endif

// Packed FP32 FMA (VOP3P). src1 low/high half broadcast via op_sel.
#define PKFMA_LO(acc, e2, v2) \
    asm("v_pk_fma_f32 %0, %1, %2, %0 op_sel:[0,0,0] op_sel_hi:[1,0,1]" \
        : "+v"(acc) : "v"(e2), "v"(v2))
#define PKFMA_HI(acc, e2, v2) \
    asm("v_pk_fma_f32 %0, %1, %2, %0 op_sel:[0,1,0] op_sel_hi:[1,1,1]" \
        : "+v"(acc) : "v"(e2), "v"(v2))

struct h4pack { __half2 lo, hi; };   // 8-byte packed store of 4 halves

// Fused scores + unnormalized per-head context, one pass over cached.
// R27 = R25 (best: 84.8us — RG=8 ping-pong, slim score, (256,2), folded k_z)
// with f16 context partials: P traffic halves (33.5->16.7 MB each way,
// ~-4.7us). Partials are O(10^2-10^3) (far from f16 max/denormals); rel err
// 5e-4 -> ~2.5e-3 output error on top of the 3.9e-3 LUT-quantization error,
// within the 1.414e-2 threshold with ~1.7x margin.
__global__ __launch_bounds__(256, 2) void k_fused(const float* __restrict__ cached,
                                                  const float* __restrict__ x,
                                                  const float* __restrict__ t,
                                                  const float* __restrict__ wq,
                                                  const float* __restrict__ bq,
                                                  const float* __restrict__ wk,
                                                  const float* __restrict__ bk,
                                                  float* __restrict__ ws) {
    __shared__ float se[2][RG][16];    // e broadcast, double-buffered (1 KB)
    int tid = threadIdx.x;
    int b = blockIdx.x >> 5;           // / NC
    int c = blockIdx.x & (NC - 1);
    int s0 = c * SC;
    int m = tid * 4;

    // per-column constants: arg_rev = v * krR + kdR  (revolutions)
    float4 wkv = *(const float4*)(wk + m);
    float4 kbv = *(const float4*)(bk + m);
    float4 krR;
    krR.x = INV2PI / (1.0f + fabsf(wkv.x));
    krR.y = INV2PI / (1.0f + fabsf(wkv.y));
    krR.z = INV2PI / (1.0f + fabsf(wkv.z));
    krR.w = INV2PI / (1.0f + fabsf(wkv.w));

    float tphi = t[b] * PHIF;
    float4 xv = *(const float4*)(x + b * ND + m);
    float4 wqv = *(const float4*)(wq + m);
    float4 bqv = *(const float4*)(bq + m);
    float4 kdR;   // bk/(2pi) - rint(theta_q*KF)*REVF  (query stays quantized)
    kdR.x = kbv.x * INV2PI - rintf((xv.x / (1.0f + fabsf(wqv.x)) + bqv.x + tphi) * KF) * REVF;
    kdR.y = kbv.y * INV2PI - rintf((xv.y / (1.0f + fabsf(wqv.y)) + bqv.y + tphi) * KF) * REVF;
    kdR.z = kbv.z * INV2PI - rintf((xv.z / (1.0f + fabsf(wqv.z)) + bqv.z + tphi) * KF) * REVF;
    kdR.w = kbv.w * INV2PI - rintf((xv.w / (1.0f + fabsf(wqv.w)) + bqv.w + tphi) * KF) * REVF;

    // acc2[p][q] = (ctxh[2p][col q], ctxh[2p+1][col q]) — 64 VGPRs
    float2 acc2[8][4];
    #pragma unroll
    for (int p = 0; p < 8; ++p)
        #pragma unroll
        for (int q = 0; q < 4; ++q) acc2[p][q] = make_float2(0.f, 0.f);
    float zacc = 0.f;

    const float* base = cached + ((size_t)b * NS + s0) * ND + m;
    float4 vA[RG], vB[RG];

#define LOADG(dst, g) { \
    const float* bp = base + (size_t)(g) * (RG * ND); \
    _Pragma("unroll") \
    for (int r = 0; r < RG; ++r) dst[r] = *(const float4*)(bp + (size_t)r * ND); }

    // slim score: one fma + one v_cos per element (v_cos takes revolutions)
#define SCOREG(v, buf) { \
    _Pragma("unroll") \
    for (int r = 0; r < RG; ++r) { \
        float c0 = __builtin_amdgcn_cosf(fmaf(v[r].x, krR.x, kdR.x)); \
        float c1 = __builtin_amdgcn_cosf(fmaf(v[r].y, krR.y, kdR.y)); \
        float c2 = __builtin_amdgcn_cosf(fmaf(v[r].z, krR.z, kdR.z)); \
        float c3 = __builtin_amdgcn_cosf(fmaf(v[r].w, krR.w, kdR.w)); \
        float p = (c0 + c1) + (c2 + c3); \
        p = dpp_reduce16(p); \
        float e = EXP2F(p * EXPC);   /* |score| <= 5.66, no max pass */ \
        zacc += e;                   /* valid in lanes 15 mod 16 */ \
        if ((tid & 15) == 15) se[buf][r][tid >> 4] = e; \
    } }

#define ACC4P(v, buf) { \
    _Pragma("unroll") \
    for (int r = 0; r < RG; ++r) { \
        const float2* s2 = (const float2*)se[buf][r]; \
        float2 vxy = make_float2(v[r].x, v[r].y); \
        float2 vzw = make_float2(v[r].z, v[r].w); \
        _Pragma("unroll") \
        for (int p = 0; p < 8; ++p) { \
            float2 e2 = s2[p]; \
            PKFMA_LO(acc2[p][0], e2, vxy); \
            PKFMA_HI(acc2[p][1], e2, vxy); \
            PKFMA_LO(acc2[p][2], e2, vzw); \
            PKFMA_HI(acc2[p][3], e2, vzw); \
        } \
    } }

    LOADG(vA, 0)
    SCOREG(vA, 0)                          // first group: latency exposed once
    for (int gp = 0; gp < NG / 2; ++gp) {
        __syncthreads();                   // se[0] visible; no loads in flight
        LOADG(vB, gp * 2 + 1)              // burst issues here; hides under ACC
        ACC4P(vA, 0)
        SCOREG(vB, 1)                      // consumes vB before next barrier
        __syncthreads();                   // se[1] visible; no loads in flight
        if (gp < NG / 2 - 1) {
            LOADG(vA, gp * 2 + 2)          // burst; hides under ACC(vB)
        }
        ACC4P(vB, 1)
        if (gp < NG / 2 - 1) {
            SCOREG(vA, 0)
        }
    }
#undef ACC4P
#undef SCOREG
#undef LOADG

    // write per-head context partials as f16 (halves P traffic), coalesced
    __half* P = (__half*)ws + (size_t)(c * NB + b) * (NH * ND) + m;
    #pragma unroll
    for (int p = 0; p < 8; ++p) {
        h4pack lo, hi;   // heads 2p (x-halves) and 2p+1 (y-halves), cols 0..3
        lo.lo = __float22half2_rn(make_float2(acc2[p][0].x, acc2[p][1].x));
        lo.hi = __float22half2_rn(make_float2(acc2[p][2].x, acc2[p][3].x));
        hi.lo = __float22half2_rn(make_float2(acc2[p][0].y, acc2[p][1].y));
        hi.hi = __float22half2_rn(make_float2(acc2[p][2].y, acc2[p][3].y));
        *(h4pack*)(P + (size_t)(2 * p) * ND) = lo;
        *(h4pack*)(P + (size_t)(2 * p + 1) * ND) = hi;
    }
    if ((tid & 15) == 15)
        ws[OFF_ZPART + (c * NB + b) * NH + (tid >> 4)] = zacc;
}

// k_out with folded Z-normalization; reads f16 partials.
__global__ __launch_bounds__(256) void k_out(const float* __restrict__ t,
                                             const float* __restrict__ wo,
                                             const float* __restrict__ bo,
                                             const float* __restrict__ osc,
                                             const float* __restrict__ ws,
                                             float* __restrict__ out) {
    __shared__ float red[4][64];
    __shared__ float sinvz[NH];
    int bid = blockIdx.x;          // NB*16 = 256
    int b = bid >> 4, mc = bid & 15;
    int tid = threadIdx.x;
    int cq = tid >> 6, ml = tid & 63;
    int m = mc * 64 + ml;
    if (tid < NH) {
        float s = 0.f;
        #pragma unroll
        for (int c = 0; c < NC; ++c)
            s += ws[OFF_ZPART + (c * NB + b) * NH + tid];
        sinvz[tid] = 1.0f / s;
    }
    __syncthreads();
    const __half* P = (const __half*)ws;
    float ctx = 0.f;
    #pragma unroll
    for (int h = 0; h < NH; ++h) {
        float s = 0.f;
        #pragma unroll
        for (int i = 0; i < NC / 4; ++i) {
            int c = cq * (NC / 4) + i;
            s += __half2float(P[(size_t)(c * NB + b) * (NH * ND) + h * ND + m]);
        }
        ctx = fmaf(s, sinvz[h], ctx);
    }
    red[cq][ml] = ctx;
    __syncthreads();
    if (cq == 0) {
        ctx = ((red[0][ml] + red[1][ml]) + (red[2][ml] + red[3][ml]));
        float theta = ctx / (1.0f + fabsf(wo[m])) + bo[m] + t[b] * PHIF;
        int idx = ((int)rintf(theta * KF)) & (LUTN - 1);
        float ang = (float)idx * (2.0f * 3.14159265358979323846f / LUTN);
        // precise libm trig: bit-matches the np table entries
        out[b * ND + m] = osc[m] * (cosf(ang) + sinf(ang));
    }
}

extern "C" void kernel_launch(void* const* d_in, const int* in_sizes, int n_in,
                              void* d_out, int out_size, void* d_ws, size_t ws_size,
                              hipStream_t stream) {
    const float* x      = (const float*)d_in[0];
    const float* cached = (const float*)d_in[1];
    const float* t      = (const float*)d_in[2];
    const float* wq     = (const float*)d_in[3];
    const float* bq     = (const float*)d_in[4];
    const float* wk     = (const float*)d_in[5];
    const float* bk     = (const float*)d_in[6];
    const float* wo     = (const float*)d_in[7];
    const float* bo     = (const float*)d_in[8];
    const float* osc    = (const float*)d_in[9];
    float* ws  = (float*)d_ws;
    float* out = (float*)d_out;

    k_fused<<<NB * NC, 256, 0, stream>>>(cached, x, t, wq, bq, wk, bk, ws);
    k_out<<<NB * (ND / 64), 256, 0, stream>>>(t, wo, bo, osc, ws, out);
}